// Round 1
// baseline (122.448 us; speedup 1.0000x reference)
//
#include <hip/hip_runtime.h>

// DCN cross network, algebraically collapsed:
//   x_i = c_i * x0 + B_i,  B_i = prefix-sum of biases (row-independent)
//   c_{i+1} = c_i + (c_i * d_i + g_i),  d_i = dot(x0, w_i),  g_i = dot(B_i, w_i)
//   out = c_4 * x0 + Bsum
//
// Layout v2: 16 lanes per row, 4 rows per wave (r = lane>>4, t = lane&15).
//  - all 4 rows' x-loads issue up front (16 float4/lane in flight)
//  - ONE 4-step butterfly reduces all 4 rows' dots simultaneously
//    (vs 4 serialized 6-step butterflies in the pipelined version)
//  - no redundant last-iteration prefetch
// Bsum lives in a per-wave LDS copy (same-wave produce/consume, no barrier)
// to keep VGPRs <= 128 (4 blocks/CU, single-pass 1024-block grid).
// Stores are nontemporal (out never re-read) so x stays L3-resident.

#define D 1024
#define NV4 (D / 4)      // 256 float4 per row
#define RPW 4            // rows per wave
#define LPR 16           // lanes per row
#define CPL (NV4 / LPR)  // 16 float4 chunks per lane

typedef float nfloat4 __attribute__((ext_vector_type(4)));  // native vec for NT store

__global__ __launch_bounds__(256, 4) void cross_flat_kernel(
    const float* __restrict__ x,
    const float* __restrict__ w,   // [4, 1024]
    const float* __restrict__ b,   // [4, 1024]
    float* __restrict__ out,
    int batch)
{
    __shared__ float4 ldsB[4][NV4];   // per-wave Bsum copy, 16 KiB/block

    const int tid  = (int)threadIdx.x;
    const int wvid = tid >> 6;
    const int lane = tid & 63;
    const int wid  = (int)blockIdx.x * 4 + wvid;
    const int row0 = wid * RPW;
    if (row0 >= batch) return;

    const int r = lane >> 4;                       // which of the wave's 4 rows
    const int t = lane & 15;                       // position within the row
    int rr = row0 + r;
    if (rr >= batch) rr = batch - 1;               // clamp (benign dup work)
    const int row = rr;

    const float4* w4 = (const float4*)w;
    const float4* b4 = (const float4*)b;

    // ---- per-wave preamble: Bsum -> LDS, g1..g3 (classic 64-lane layout) ----
    float g1 = 0.f, g2 = 0.f, g3 = 0.f;
#pragma unroll
    for (int c = 0; c < 4; ++c) {
        const int idx = c * 64 + lane;
        float4 bb0 = b4[idx], bb1 = b4[256 + idx];
        float4 bb2 = b4[512 + idx], bb3 = b4[768 + idx];
        float4 wv1 = w4[256 + idx], wv2 = w4[512 + idx], wv3 = w4[768 + idx];

        float4 B2, B3, Bs;
        B2.x = bb0.x + bb1.x; B2.y = bb0.y + bb1.y;
        B2.z = bb0.z + bb1.z; B2.w = bb0.w + bb1.w;
        B3.x = B2.x + bb2.x;  B3.y = B2.y + bb2.y;
        B3.z = B2.z + bb2.z;  B3.w = B2.w + bb2.w;
        Bs.x = B3.x + bb3.x;  Bs.y = B3.y + bb3.y;
        Bs.z = B3.z + bb3.z;  Bs.w = B3.w + bb3.w;
        ldsB[wvid][idx] = Bs;

        g1 = fmaf(bb0.x, wv1.x, g1); g1 = fmaf(bb0.y, wv1.y, g1);
        g1 = fmaf(bb0.z, wv1.z, g1); g1 = fmaf(bb0.w, wv1.w, g1);
        g2 = fmaf(B2.x,  wv2.x, g2); g2 = fmaf(B2.y,  wv2.y, g2);
        g2 = fmaf(B2.z,  wv2.z, g2); g2 = fmaf(B2.w,  wv2.w, g2);
        g3 = fmaf(B3.x,  wv3.x, g3); g3 = fmaf(B3.y,  wv3.y, g3);
        g3 = fmaf(B3.z,  wv3.z, g3); g3 = fmaf(B3.w,  wv3.w, g3);
    }

    // ---- issue ALL x loads for the wave's 4 rows (16 float4/lane in flight) ----
    const float4* xr = (const float4*)x + (size_t)row * NV4;
    float4 xv[CPL];
#pragma unroll
    for (int c = 0; c < CPL; ++c) xv[c] = xr[c * LPR + t];

    // g-butterfly overlaps the x-load latency
#pragma unroll
    for (int off = 32; off > 0; off >>= 1) {
        g1 += __shfl_xor(g1, off, 64);
        g2 += __shfl_xor(g2, off, 64);
        g3 += __shfl_xor(g3, off, 64);
    }

    // ---- 4 layer-dots over this lane's 64 elements of its row ----
    float d0 = 0.f, d1 = 0.f, d2 = 0.f, d3 = 0.f;
#pragma unroll
    for (int c = 0; c < CPL; ++c) {
        const int wi = c * LPR + t;
        float4 wv0 = w4[wi];
        float4 wv1 = w4[256 + wi];
        float4 wv2 = w4[512 + wi];
        float4 wv3 = w4[768 + wi];
        float4 xc = xv[c];
        d0 = fmaf(xc.x, wv0.x, d0); d1 = fmaf(xc.x, wv1.x, d1);
        d2 = fmaf(xc.x, wv2.x, d2); d3 = fmaf(xc.x, wv3.x, d3);
        d0 = fmaf(xc.y, wv0.y, d0); d1 = fmaf(xc.y, wv1.y, d1);
        d2 = fmaf(xc.y, wv2.y, d2); d3 = fmaf(xc.y, wv3.y, d3);
        d0 = fmaf(xc.z, wv0.z, d0); d1 = fmaf(xc.z, wv1.z, d1);
        d2 = fmaf(xc.z, wv2.z, d2); d3 = fmaf(xc.z, wv3.z, d3);
        d0 = fmaf(xc.w, wv0.w, d0); d1 = fmaf(xc.w, wv1.w, d1);
        d2 = fmaf(xc.w, wv2.w, d2); d3 = fmaf(xc.w, wv3.w, d3);
    }

    // ---- ONE 4-step butterfly reduces all 4 rows at once (within 16-lane groups) ----
#pragma unroll
    for (int off = 8; off > 0; off >>= 1) {
        d0 += __shfl_xor(d0, off, 64);
        d1 += __shfl_xor(d1, off, 64);
        d2 += __shfl_xor(d2, off, 64);
        d3 += __shfl_xor(d3, off, 64);
    }

    const float c1 = 1.f + d0;
    const float c2 = c1 + fmaf(c1, d1, g1);
    const float c3 = c2 + fmaf(c2, d2, g2);
    const float c4 = c3 + fmaf(c3, d3, g3);

    // ---- epilogue: out = c4 * x0 + Bsum, nontemporal ----
    nfloat4* orow = (nfloat4*)out + (size_t)row * NV4;
#pragma unroll
    for (int c = 0; c < CPL; ++c) {
        const int wi = c * LPR + t;
        float4 Bs = ldsB[wvid][wi];
        nfloat4 o;
        o.x = fmaf(c4, xv[c].x, Bs.x);
        o.y = fmaf(c4, xv[c].y, Bs.y);
        o.z = fmaf(c4, xv[c].z, Bs.z);
        o.w = fmaf(c4, xv[c].w, Bs.w);
        __builtin_nontemporal_store(o, &orow[wi]);
    }
}

extern "C" void kernel_launch(void* const* d_in, const int* in_sizes, int n_in,
                              void* d_out, int out_size, void* d_ws, size_t ws_size,
                              hipStream_t stream) {
    const float* x = (const float*)d_in[0];
    const float* w = (const float*)d_in[1];
    const float* b = (const float*)d_in[2];
    float* out = (float*)d_out;

    const int batch = in_sizes[0] / D;              // 16384
    const int rows_per_block = RPW * (256 / 64);    // 16 rows per block
    const int grid = (batch + rows_per_block - 1) / rows_per_block;  // 1024
    cross_flat_kernel<<<grid, 256, 0, stream>>>(x, w, b, out, batch);
}